// Round 1
// baseline (290.671 us; speedup 1.0000x reference)
//
#include <hip/hip_runtime.h>
#include <stdint.h>

#define NN 2048
#define DD 1024
#define HH 16
#define HDD 64
#define QBLK 64
#define KVBLK 64

typedef unsigned short u16;
typedef __attribute__((ext_vector_type(8))) __bf16 bf16x8_t;
typedef __attribute__((ext_vector_type(4))) float f32x4_t;

static __device__ __forceinline__ u16 f2bf(float f) {
  union { float f; uint32_t u; } v; v.f = f;
  uint32_t r = v.u + 0x7FFFu + ((v.u >> 16) & 1u);
  return (u16)(r >> 16);
}

// ---------------- cast x (fp32 -> bf16) ----------------
__global__ void cast_x_kernel(const float* __restrict__ x, u16* __restrict__ xb) {
  int i = blockIdx.x * blockDim.x + threadIdx.x;  // each handles 4 elems
  float4 v = *(const float4*)&x[i * 4];
  ushort4 o;
  o.x = f2bf(v.x); o.y = f2bf(v.y); o.z = f2bf(v.z); o.w = f2bf(v.w);
  *(ushort4*)&xb[i * 4] = o;
}

// ---------------- weight transpose+cast: Wt[n][k] = W[k][n] ----------------
__global__ void transpose_w_kernel(const float* __restrict__ W, u16* __restrict__ Wt) {
  __shared__ float tile[64][65];
  int bx = blockIdx.x & 15;   // n tile
  int by = blockIdx.x >> 4;   // k tile
  int t = threadIdx.x;
  int c = t & 63, r4 = t >> 6;
#pragma unroll
  for (int i = 0; i < 16; i++) {
    int row = i * 4 + r4;
    tile[row][c] = W[(by * 64 + row) * DD + bx * 64 + c];
  }
  __syncthreads();
#pragma unroll
  for (int i = 0; i < 16; i++) {
    int row = i * 4 + r4;
    Wt[(bx * 64 + row) * DD + by * 64 + c] = f2bf(tile[c][row]);
  }
}

// ---------------- log-sigmoid gate: lf[bh][n] ----------------
__global__ void logf_kernel(const float* __restrict__ x, const float* __restrict__ Wf,
                            float* __restrict__ lf) {
  __shared__ float xs[DD];
  __shared__ float part[16][17];
  int row = blockIdx.x;   // b*N + n
  int t = threadIdx.x;    // 256
  *(float4*)&xs[t * 4] = *(const float4*)&x[(size_t)row * DD + t * 4];
  __syncthreads();
  int h = t & 15, chunk = t >> 4;
  float s = 0.f;
#pragma unroll 8
  for (int e = 0; e < 64; e++)
    s += xs[chunk * 64 + e] * Wf[(chunk * 64 + e) * HH + h];
  part[chunk][h] = s;
  __syncthreads();
  if (t < 16) {
    float z = 0.f;
#pragma unroll
    for (int i = 0; i < 16; i++) z += part[i][t];
    float ls = fminf(z, 0.f) - log1pf(__expf(-fabsf(z)));
    int b = row >> 11, n = row & (NN - 1);
    lf[(b * HH + t) * NN + n] = ls;
  }
}

// ---------------- cumsum over n per (b,h) ----------------
__global__ void cumsum_kernel(const float* __restrict__ lf, float* __restrict__ c) {
  int bh = blockIdx.x;
  int lane = threadIdx.x;  // 64
  const float* in = lf + bh * NN;
  float* out = c + bh * NN;
  float carry = 0.f;
  for (int t0 = 0; t0 < NN; t0 += 64) {
    float v = in[t0 + lane];
#pragma unroll
    for (int off = 1; off < 64; off <<= 1) {
      float u = __shfl_up(v, off, 64);
      if (lane >= off) v += u;
    }
    v += carry;
    out[t0 + lane] = v;
    carry = __shfl(v, 63, 64);
  }
}

// ---------------- GEMM: [4096x1024] x Wt[n][k] -> out ----------------
// mode 0: bf16 out at [bh][n][hd]; mode 1: fp32 out flat [row][col]
__global__ __launch_bounds__(256) void gemm_kernel(const u16* __restrict__ A,
                                                   const u16* __restrict__ Wt,
                                                   void* __restrict__ outp, int mode) {
  __shared__ u16 Als[128 * 32];
  __shared__ u16 Bls[128 * 32];
  int m0 = blockIdx.y * 128, n0 = blockIdx.x * 128;
  int tid = threadIdx.x;
  int lane = tid & 63, w = tid >> 6;
  int wm = w >> 1, wn = w & 1;
  int lr = lane & 15, lg = lane >> 4;
  f32x4_t acc[4][4];
#pragma unroll
  for (int i = 0; i < 4; i++)
#pragma unroll
    for (int j = 0; j < 4; j++) acc[i][j] = (f32x4_t){0.f, 0.f, 0.f, 0.f};

  for (int kt = 0; kt < DD; kt += 32) {
    __syncthreads();
#pragma unroll
    for (int it = 0; it < 2; it++) {
      int cc = tid + it * 256;
      int row = cc >> 2, p = cc & 3;
      *(uint4*)&Als[row * 32 + p * 8] = *(const uint4*)&A[(size_t)(m0 + row) * DD + kt + p * 8];
      *(uint4*)&Bls[row * 32 + p * 8] = *(const uint4*)&Wt[(size_t)(n0 + row) * DD + kt + p * 8];
    }
    __syncthreads();
    bf16x8_t af[4], bfv[4];
#pragma unroll
    for (int mi = 0; mi < 4; mi++)
      af[mi] = *(const bf16x8_t*)&Als[(wm * 64 + mi * 16 + lr) * 32 + lg * 8];
#pragma unroll
    for (int ni = 0; ni < 4; ni++)
      bfv[ni] = *(const bf16x8_t*)&Bls[(wn * 64 + ni * 16 + lr) * 32 + lg * 8];
#pragma unroll
    for (int mi = 0; mi < 4; mi++)
#pragma unroll
      for (int ni = 0; ni < 4; ni++)
        acc[mi][ni] = __builtin_amdgcn_mfma_f32_16x16x32_bf16(af[mi], bfv[ni], acc[mi][ni], 0, 0, 0);
  }

#pragma unroll
  for (int mi = 0; mi < 4; mi++) {
#pragma unroll
    for (int ni = 0; ni < 4; ni++) {
      int gcol = n0 + wn * 64 + ni * 16 + lr;
#pragma unroll
      for (int r = 0; r < 4; r++) {
        int grow = m0 + wm * 64 + mi * 16 + lg * 4 + r;
        float v = acc[mi][ni][r];
        if (mode == 1) {
          ((float*)outp)[(size_t)grow * DD + gcol] = v;
        } else {
          int b = grow >> 11, n = grow & (NN - 1);
          int h = gcol >> 6, hd = gcol & 63;
          ((u16*)outp)[((size_t)(b * HH + h) * NN + n) * HDD + hd] = f2bf(v);
        }
      }
    }
  }
}

// ---------------- V transpose: [bh][n][hd] -> [bh][hd][n] ----------------
__global__ void transpose_v_kernel(const u16* __restrict__ Vtmp, u16* __restrict__ Vt) {
  __shared__ u16 tile[64][80];
  int bh = blockIdx.y;
  int n0 = blockIdx.x * 64;
  int t = threadIdx.x;
  const u16* src = Vtmp + (size_t)bh * NN * HDD;
  u16* dst = Vt + (size_t)bh * HDD * NN;
#pragma unroll
  for (int it = 0; it < 2; it++) {
    int cc = t + it * 256;
    int row = cc >> 3, p = cc & 7;  // row: n-local, p: hd chunk
    *(uint4*)&tile[row][p * 8] = *(const uint4*)&src[(size_t)(n0 + row) * HDD + p * 8];
  }
  __syncthreads();
#pragma unroll
  for (int it = 0; it < 2; it++) {
    int cc = t + it * 256;
    int row = cc >> 3, p = cc & 7;  // row: hd-local, p: n chunk
    union { u16 v[8]; uint4 q; } tmp;
#pragma unroll
    for (int e = 0; e < 8; e++) tmp.v[e] = tile[p * 8 + e][row];
    *(uint4*)&dst[(size_t)row * NN + n0 + p * 8] = tmp.q;
  }
}

// ---------------- flash attention with decay bias ----------------
__global__ __launch_bounds__(256) void attn_kernel(const u16* __restrict__ Q,
                                                   const u16* __restrict__ K,
                                                   const u16* __restrict__ Vt,
                                                   const float* __restrict__ cw,
                                                   u16* __restrict__ O) {
  __shared__ u16 Kls[KVBLK * 64];
  __shared__ u16 Vls[64 * KVBLK];
  __shared__ u16 Pls[4][16 * 64];
  int tile = blockIdx.x, bh = blockIdx.y;
  int tid = threadIdx.x;
  int lane = tid & 63, w = tid >> 6;
  int lr = lane & 15, lg = lane >> 4;
  const u16* Qh = Q + (size_t)bh * NN * HDD;
  const u16* Kh = K + (size_t)bh * NN * HDD;
  const u16* Vh = Vt + (size_t)bh * HDD * NN;
  const float* ch = cw + bh * NN;
  int qb = tile * QBLK + w * 16;

  bf16x8_t qf[2];
#pragma unroll
  for (int s = 0; s < 2; s++)
    qf[s] = *(const bf16x8_t*)&Qh[(size_t)(qb + lr) * HDD + s * 32 + lg * 8];
  float cq[4];
#pragma unroll
  for (int r = 0; r < 4; r++) cq[r] = ch[qb + lg * 4 + r];

  float m_st[4], l_st[4];
  f32x4_t oacc[4];
#pragma unroll
  for (int r = 0; r < 4; r++) { m_st[r] = -1e30f; l_st[r] = 0.f; }
#pragma unroll
  for (int fn = 0; fn < 4; fn++) oacc[fn] = (f32x4_t){0.f, 0.f, 0.f, 0.f};

  int nkv = tile + 1;
  for (int kvt = 0; kvt < nkv; kvt++) {
    int kv0 = kvt * KVBLK;
    __syncthreads();
    // stage K and V tiles, XOR-swizzled rows (row-major 128B rows -> 32-way conflict otherwise)
#pragma unroll
    for (int it = 0; it < 2; it++) {
      int cc = tid + it * 256;
      int row = cc >> 3, p = cc & 7;
      int boff = (row * 128 + p * 16) ^ ((row & 7) << 4);
      *(uint4*)((char*)Kls + boff) = *(const uint4*)&Kh[(size_t)(kv0 + row) * HDD + p * 8];
      *(uint4*)((char*)Vls + boff) = *(const uint4*)&Vh[(size_t)row * NN + kv0 + p * 8];
    }
    __syncthreads();
    float ck[4];
#pragma unroll
    for (int f = 0; f < 4; f++) ck[f] = ch[kv0 + f * 16 + lr];

    // QK^T
    f32x4_t sacc[4];
#pragma unroll
    for (int f = 0; f < 4; f++) sacc[f] = (f32x4_t){0.f, 0.f, 0.f, 0.f};
#pragma unroll
    for (int f = 0; f < 4; f++) {
      int row = f * 16 + lr;
#pragma unroll
      for (int s = 0; s < 2; s++) {
        int boff = (row * 128 + s * 64 + lg * 16) ^ ((row & 7) << 4);
        bf16x8_t kf = *(const bf16x8_t*)((const char*)Kls + boff);
        sacc[f] = __builtin_amdgcn_mfma_f32_16x16x32_bf16(qf[s], kf, sacc[f], 0, 0, 0);
      }
    }

    // decay bias + causal mask + online softmax
    bool diag = (kvt == tile);
    float p[4][4];
    float pm[4] = {-1e30f, -1e30f, -1e30f, -1e30f};
#pragma unroll
    for (int f = 0; f < 4; f++) {
      int j = kv0 + f * 16 + lr;
#pragma unroll
      for (int r = 0; r < 4; r++) {
        float val = sacc[f][r] * 0.125f + (cq[r] - ck[f]);
        if (diag && j > qb + lg * 4 + r) val = -1e30f;
        p[f][r] = val;
        pm[r] = fmaxf(pm[r], val);
      }
    }
#pragma unroll
    for (int mask = 1; mask < 16; mask <<= 1)
#pragma unroll
      for (int r = 0; r < 4; r++)
        pm[r] = fmaxf(pm[r], __shfl_xor(pm[r], mask, 64));

#pragma unroll
    for (int r = 0; r < 4; r++) {
      float mn = fmaxf(m_st[r], pm[r]);
      float sc = __expf(m_st[r] - mn);
      m_st[r] = mn;
      l_st[r] *= sc;
#pragma unroll
      for (int fn = 0; fn < 4; fn++) oacc[fn][r] *= sc;
    }
    float rs[4] = {0.f, 0.f, 0.f, 0.f};
#pragma unroll
    for (int f = 0; f < 4; f++)
#pragma unroll
      for (int r = 0; r < 4; r++) {
        p[f][r] = __expf(p[f][r] - m_st[r]);
        rs[r] += p[f][r];
      }
#pragma unroll
    for (int mask = 1; mask < 16; mask <<= 1)
#pragma unroll
      for (int r = 0; r < 4; r++)
        rs[r] += __shfl_xor(rs[r], mask, 64);
#pragma unroll
    for (int r = 0; r < 4; r++) l_st[r] += rs[r];

    // P -> LDS (D-layout write, A-layout read), swizzled
    u16* pw = (u16*)Pls[w];
#pragma unroll
    for (int f = 0; f < 4; f++)
#pragma unroll
      for (int r = 0; r < 4; r++) {
        int row = lg * 4 + r, col = f * 16 + lr;
        int boff = (row * 128 + col * 2) ^ ((row & 7) << 4);
        *(u16*)((char*)pw + boff) = f2bf(p[f][r]);
      }
    __syncthreads();

    // PV
    bf16x8_t pa[2];
#pragma unroll
    for (int s = 0; s < 2; s++) {
      int boff = (lr * 128 + s * 64 + lg * 16) ^ ((lr & 7) << 4);
      pa[s] = *(const bf16x8_t*)((const char*)pw + boff);
    }
#pragma unroll
    for (int fn = 0; fn < 4; fn++) {
      int row = fn * 16 + lr;
#pragma unroll
      for (int s = 0; s < 2; s++) {
        int boff = (row * 128 + s * 64 + lg * 16) ^ ((row & 7) << 4);
        bf16x8_t vf = *(const bf16x8_t*)((const char*)Vls + boff);
        oacc[fn] = __builtin_amdgcn_mfma_f32_16x16x32_bf16(pa[s], vf, oacc[fn], 0, 0, 0);
      }
    }
  }

  int b = bh >> 4, h = bh & 15;
#pragma unroll
  for (int fn = 0; fn < 4; fn++)
#pragma unroll
    for (int r = 0; r < 4; r++) {
      int n_idx = qb + lg * 4 + r;
      float v = oacc[fn][r] / l_st[r];
      O[((size_t)(b * NN + n_idx)) * DD + h * HDD + fn * 16 + lr] = f2bf(v);
    }
}

extern "C" void kernel_launch(void* const* d_in, const int* in_sizes, int n_in,
                              void* d_out, int out_size, void* d_ws, size_t ws_size,
                              hipStream_t stream) {
  const float* x  = (const float*)d_in[0];
  const float* Wq = (const float*)d_in[1];
  const float* Wk = (const float*)d_in[2];
  const float* Wv = (const float*)d_in[3];
  const float* Wo = (const float*)d_in[4];
  const float* Wf = (const float*)d_in[5];
  float* out = (float*)d_out;
  char* ws = (char*)d_ws;
  const size_t MB = 1024 * 1024;
  u16* x_bf = (u16*)(ws + 0);        // 8 MB
  u16* WqT  = (u16*)(ws + 8  * MB);  // 2 MB each
  u16* WkT  = (u16*)(ws + 10 * MB);
  u16* WvT  = (u16*)(ws + 12 * MB);
  u16* WoT  = (u16*)(ws + 14 * MB);
  u16* Qw   = (u16*)(ws + 16 * MB);  // 8 MB [bh][n][hd]
  u16* Kw   = (u16*)(ws + 24 * MB);  // 8 MB
  u16* Vw   = (u16*)(ws + 32 * MB);  // 8 MB [bh][hd][n]
  u16* Ow   = (u16*)(ws + 40 * MB);  // 8 MB [b n d]
  float* lf = (float*)(ws + 48 * MB);            // 256 KB
  float* cwp = (float*)(ws + 48 * MB + 262144);  // 256 KB
  u16* Vtmp = (u16*)(ws + 49 * MB);  // 8 MB [bh][n][hd]

  cast_x_kernel<<<4096, 256, 0, stream>>>(x, x_bf);
  transpose_w_kernel<<<256, 256, 0, stream>>>(Wq, WqT);
  transpose_w_kernel<<<256, 256, 0, stream>>>(Wk, WkT);
  transpose_w_kernel<<<256, 256, 0, stream>>>(Wv, WvT);
  transpose_w_kernel<<<256, 256, 0, stream>>>(Wo, WoT);
  logf_kernel<<<4096, 256, 0, stream>>>(x, Wf, lf);
  cumsum_kernel<<<32, 64, 0, stream>>>(lf, cwp);
  dim3 gg(8, 32);
  gemm_kernel<<<gg, 256, 0, stream>>>(x_bf, WqT, Qw, 0);
  gemm_kernel<<<gg, 256, 0, stream>>>(x_bf, WkT, Kw, 0);
  gemm_kernel<<<gg, 256, 0, stream>>>(x_bf, WvT, Vtmp, 0);
  transpose_v_kernel<<<dim3(32, 32), 256, 0, stream>>>(Vtmp, Vw);
  attn_kernel<<<dim3(32, 32), 256, 0, stream>>>(Qw, Kw, Vw, cwp, Ow);
  gemm_kernel<<<gg, 256, 0, stream>>>(Ow, WoT, out, 1);
}

// Round 3
// 218.873 us; speedup vs baseline: 1.3280x; 1.3280x over previous
//
#include <hip/hip_runtime.h>
#include <stdint.h>

#define NN 2048
#define DD 1024
#define HH 16
#define HDD 64
#define QBLK 64
#define KVBLK 64

typedef unsigned short u16;
typedef __attribute__((ext_vector_type(8))) __bf16 bf16x8_t;
typedef __attribute__((ext_vector_type(4))) float f32x4_t;

static __device__ __forceinline__ u16 f2bf(float f) {
  union { float f; uint32_t u; } v; v.f = f;
  uint32_t r = v.u + 0x7FFFu + ((v.u >> 16) & 1u);
  return (u16)(r >> 16);
}

// async global->LDS, 16B per lane. LDS dest must be wave-uniform base + lane*16
// (callers pass tid-linear offsets so this holds).
static __device__ __forceinline__ void async_copy16(const void* g, void* l) {
  __builtin_amdgcn_global_load_lds((const __attribute__((address_space(1))) void*)g,
                                   (__attribute__((address_space(3))) void*)l, 16, 0, 0);
}

// ---------------- weight transpose+cast: Wt[n][k] = W[k][n] ----------------
__global__ void transpose_w_kernel(const float* __restrict__ W, u16* __restrict__ Wt) {
  __shared__ float tile[64][65];
  int bx = blockIdx.x & 15;   // n tile
  int by = blockIdx.x >> 4;   // k tile
  int t = threadIdx.x;
  int c = t & 63, r4 = t >> 6;
#pragma unroll
  for (int i = 0; i < 16; i++) {
    int row = i * 4 + r4;
    tile[row][c] = W[(by * 64 + row) * DD + bx * 64 + c];
  }
  __syncthreads();
#pragma unroll
  for (int i = 0; i < 16; i++) {
    int row = i * 4 + r4;
    Wt[(bx * 64 + row) * DD + by * 64 + c] = f2bf(tile[c][row]);
  }
}

// ---------------- log-sigmoid gate + fused x->bf16 cast ----------------
__global__ void logf_kernel(const float* __restrict__ x, const float* __restrict__ Wf,
                            float* __restrict__ lf, u16* __restrict__ xb) {
  __shared__ float xs[DD];
  __shared__ float part[16][17];
  int row = blockIdx.x;   // b*N + n
  int t = threadIdx.x;    // 256
  float4 v = *(const float4*)&x[(size_t)row * DD + t * 4];
  *(float4*)&xs[t * 4] = v;
  ushort4 o;
  o.x = f2bf(v.x); o.y = f2bf(v.y); o.z = f2bf(v.z); o.w = f2bf(v.w);
  *(ushort4*)&xb[(size_t)row * DD + t * 4] = o;
  __syncthreads();
  int h = t & 15, chunk = t >> 4;
  float s = 0.f;
#pragma unroll 8
  for (int e = 0; e < 64; e++)
    s += xs[chunk * 64 + e] * Wf[(chunk * 64 + e) * HH + h];
  part[chunk][h] = s;
  __syncthreads();
  if (t < 16) {
    float z = 0.f;
#pragma unroll
    for (int i = 0; i < 16; i++) z += part[i][t];
    float ls = fminf(z, 0.f) - log1pf(__expf(-fabsf(z)));
    int b = row >> 11, n = row & (NN - 1);
    lf[(b * HH + t) * NN + n] = ls;
  }
}

// ---------------- cumsum over n per (b,h) ----------------
__global__ void cumsum_kernel(const float* __restrict__ lf, float* __restrict__ c) {
  int bh = blockIdx.x;
  int lane = threadIdx.x;  // 64
  const float* in = lf + bh * NN;
  float* out = c + bh * NN;
  float carry = 0.f;
  for (int t0 = 0; t0 < NN; t0 += 64) {
    float v = in[t0 + lane];
#pragma unroll
    for (int off = 1; off < 64; off <<= 1) {
      float u = __shfl_up(v, off, 64);
      if (lane >= off) v += u;
    }
    v += carry;
    out[t0 + lane] = v;
    carry = __shfl(v, 63, 64);
  }
}

// ---------------- GEMM: [4096x1024] x Wt[n][k] -> out (m97 structure) ----------------
// mode 0: bf16 out at [bh][n][hd]; mode 1: fp32 out flat [row][col]
__global__ __launch_bounds__(256) void gemm_kernel(const u16* __restrict__ A,
                                                   const u16* __restrict__ Wt,
                                                   void* __restrict__ outp, int mode) {
  __shared__ u16 Als[128 * 32];
  __shared__ u16 Bls[128 * 32];
  int m0 = blockIdx.y * 128, n0 = blockIdx.x * 128;
  int tid = threadIdx.x;
  int lane = tid & 63, w = tid >> 6;
  int wm = w >> 1, wn = w & 1;
  int lr = lane & 15, lg = lane >> 4;
  // staging: linear LDS [128][32], byte b = tid*16 (+it*4096): row=b/64, col elems (b%64)/2
  int srow = tid >> 2, scol = (tid & 3) * 8;
  const u16* ga0 = &A [(size_t)(m0 + srow) * DD + scol];
  const u16* ga1 = &A [(size_t)(m0 + 64 + srow) * DD + scol];
  const u16* gb0 = &Wt[(size_t)(n0 + srow) * DD + scol];
  const u16* gb1 = &Wt[(size_t)(n0 + 64 + srow) * DD + scol];
  u16* la0 = &Als[tid * 8];
  u16* la1 = &Als[2048 + tid * 8];
  u16* lb0 = &Bls[tid * 8];
  u16* lb1 = &Bls[2048 + tid * 8];

  f32x4_t acc[4][4];
#pragma unroll
  for (int i = 0; i < 4; i++)
#pragma unroll
    for (int j = 0; j < 4; j++) acc[i][j] = (f32x4_t){0.f, 0.f, 0.f, 0.f};

  for (int kt = 0; kt < DD; kt += 32) {
    __syncthreads();
    async_copy16(ga0 + kt, la0);
    async_copy16(ga1 + kt, la1);
    async_copy16(gb0 + kt, lb0);
    async_copy16(gb1 + kt, lb1);
    __syncthreads();
    bf16x8_t af[4], bfv[4];
#pragma unroll
    for (int mi = 0; mi < 4; mi++)
      af[mi] = *(const bf16x8_t*)&Als[(wm * 64 + mi * 16 + lr) * 32 + lg * 8];
#pragma unroll
    for (int ni = 0; ni < 4; ni++)
      bfv[ni] = *(const bf16x8_t*)&Bls[(wn * 64 + ni * 16 + lr) * 32 + lg * 8];
#pragma unroll
    for (int mi = 0; mi < 4; mi++)
#pragma unroll
      for (int ni = 0; ni < 4; ni++)
        acc[mi][ni] = __builtin_amdgcn_mfma_f32_16x16x32_bf16(af[mi], bfv[ni], acc[mi][ni], 0, 0, 0);
  }

#pragma unroll
  for (int mi = 0; mi < 4; mi++) {
#pragma unroll
    for (int ni = 0; ni < 4; ni++) {
      int gcol = n0 + wn * 64 + ni * 16 + lr;
#pragma unroll
      for (int r = 0; r < 4; r++) {
        int grow = m0 + wm * 64 + mi * 16 + lg * 4 + r;
        float v = acc[mi][ni][r];
        if (mode == 1) {
          ((float*)outp)[(size_t)grow * DD + gcol] = v;
        } else {
          int b = grow >> 11, n = grow & (NN - 1);
          int h = gcol >> 6, hd = gcol & 63;
          ((u16*)outp)[((size_t)(b * HH + h) * NN + n) * HDD + hd] = f2bf(v);
        }
      }
    }
  }
}

// ---------------- V transpose: [bh][n][hd] -> [bh][hd][n] ----------------
__global__ void transpose_v_kernel(const u16* __restrict__ Vtmp, u16* __restrict__ Vt) {
  __shared__ u16 tile[64][80];
  int bh = blockIdx.y;
  int n0 = blockIdx.x * 64;
  int t = threadIdx.x;
  const u16* src = Vtmp + (size_t)bh * NN * HDD;
  u16* dst = Vt + (size_t)bh * HDD * NN;
#pragma unroll
  for (int it = 0; it < 2; it++) {
    int cc = t + it * 256;
    int row = cc >> 3, p = cc & 7;
    *(uint4*)&tile[row][p * 8] = *(const uint4*)&src[(size_t)(n0 + row) * HDD + p * 8];
  }
  __syncthreads();
#pragma unroll
  for (int it = 0; it < 2; it++) {
    int cc = t + it * 256;
    int row = cc >> 3, p = cc & 7;
    union { u16 v[8]; uint4 q; } tmp;
#pragma unroll
    for (int e = 0; e < 8; e++) tmp.v[e] = tile[p * 8 + e][row];
    *(uint4*)&dst[(size_t)row * NN + n0 + p * 8] = tmp.q;
  }
}

// ---------------- flash attention with decay bias ----------------
// Fixed-max softmax (scores structurally bounded: qk*scale ~ +-1, c_i-c_j <= 0),
// deferred l-reduction, paired q-tiles (t, 31-t) for balanced work.
__global__ __launch_bounds__(256) void attn_kernel(const u16* __restrict__ Q,
                                                   const u16* __restrict__ K,
                                                   const u16* __restrict__ Vt,
                                                   const float* __restrict__ cw,
                                                   u16* __restrict__ O) {
  __shared__ u16 Kls[KVBLK * 64];
  __shared__ u16 Vls[64 * KVBLK];
  __shared__ u16 Pls[4][16 * 64];
  int pidx = blockIdx.x, bh = blockIdx.y;
  int tid = threadIdx.x;
  int lane = tid & 63, w = tid >> 6;
  int lr = lane & 15, lg = lane >> 4;
  const u16* Qh = Q + (size_t)bh * NN * HDD;
  const u16* Kh = K + (size_t)bh * NN * HDD;
  const u16* Vh = Vt + (size_t)bh * HDD * NN;
  const float* ch = cw + bh * NN;
  int b = bh >> 4, h = bh & 15;

  // staging geometry: 512 slots of 16B per 8KB tile; slot -> (row=slot>>3, chunk=slot&7),
  // LDS linear at slot*16B; swizzle folded into SOURCE chunk: chunk ^ (row&7).
  int s0 = tid, s1 = tid + 256;
  int r0 = s0 >> 3, p0 = s0 & 7;
  int r1 = s1 >> 3, p1 = s1 & 7;
  const u16* gk0 = &Kh[(size_t)r0 * HDD + ((p0 ^ (r0 & 7)) * 8)];
  const u16* gk1 = &Kh[(size_t)r1 * HDD + ((p1 ^ (r1 & 7)) * 8)];
  const u16* gv0 = &Vh[(size_t)r0 * NN + ((p0 ^ (r0 & 7)) * 8)];
  const u16* gv1 = &Vh[(size_t)r1 * NN + ((p1 ^ (r1 & 7)) * 8)];
  u16* lk0 = &Kls[s0 * 8];
  u16* lk1 = &Kls[s1 * 8];
  u16* lv0 = &Vls[s0 * 8];
  u16* lv1 = &Vls[s1 * 8];

  for (int which = 0; which < 2; which++) {
    int tile = which == 0 ? (31 - pidx) : pidx;
    int qb = tile * QBLK + w * 16;

    bf16x8_t qf[2];
#pragma unroll
    for (int s = 0; s < 2; s++)
      qf[s] = *(const bf16x8_t*)&Qh[(size_t)(qb + lr) * HDD + s * 32 + lg * 8];
    float cq[4];
#pragma unroll
    for (int r = 0; r < 4; r++) cq[r] = ch[qb + lg * 4 + r];

    float lsum[4] = {0.f, 0.f, 0.f, 0.f};
    f32x4_t oacc[4];
#pragma unroll
    for (int fn = 0; fn < 4; fn++) oacc[fn] = (f32x4_t){0.f, 0.f, 0.f, 0.f};

    for (int kvt = 0; kvt <= tile; kvt++) {
      int kv0 = kvt * KVBLK;
      __syncthreads();
      async_copy16(gk0 + (size_t)kv0 * HDD, lk0);
      async_copy16(gk1 + (size_t)kv0 * HDD, lk1);
      async_copy16(gv0 + kv0, lv0);
      async_copy16(gv1 + kv0, lv1);
      __syncthreads();
      float ck[4];
#pragma unroll
      for (int f = 0; f < 4; f++) ck[f] = ch[kv0 + f * 16 + lr];

      // QK^T
      f32x4_t sacc[4];
#pragma unroll
      for (int f = 0; f < 4; f++) sacc[f] = (f32x4_t){0.f, 0.f, 0.f, 0.f};
#pragma unroll
      for (int f = 0; f < 4; f++) {
        int row = f * 16 + lr;
#pragma unroll
        for (int s = 0; s < 2; s++) {
          int boff = (row * 128 + s * 64 + lg * 16) ^ ((row & 7) << 4);
          bf16x8_t kf = *(const bf16x8_t*)((const char*)Kls + boff);
          sacc[f] = __builtin_amdgcn_mfma_f32_16x16x32_bf16(qf[s], kf, sacc[f], 0, 0, 0);
        }
      }

      // fixed-max softmax: p = exp(score); accumulate per-lane partial l
      bool diag = (kvt == tile);
      float pv[4][4];
      if (diag) {
#pragma unroll
        for (int f = 0; f < 4; f++) {
          int j = kv0 + f * 16 + lr;
#pragma unroll
          for (int r = 0; r < 4; r++) {
            float val = fmaf(sacc[f][r], 0.125f, cq[r] - ck[f]);
            if (j > qb + lg * 4 + r) val = -1e30f;
            float e = __expf(val);
            pv[f][r] = e; lsum[r] += e;
          }
        }
      } else {
#pragma unroll
        for (int f = 0; f < 4; f++)
#pragma unroll
          for (int r = 0; r < 4; r++) {
            float val = fmaf(sacc[f][r], 0.125f, cq[r] - ck[f]);
            float e = __expf(val);
            pv[f][r] = e; lsum[r] += e;
          }
      }

      // P -> LDS (D-layout write, A-layout read), per-wave buffer, swizzled.
      // No barrier needed: same-wave LDS ops are ordered; compiler inserts lgkmcnt.
      u16* pw = (u16*)Pls[w];
#pragma unroll
      for (int f = 0; f < 4; f++)
#pragma unroll
        for (int r = 0; r < 4; r++) {
          int row = lg * 4 + r, col = f * 16 + lr;
          int boff = (row * 128 + col * 2) ^ ((row & 7) << 4);
          *(u16*)((char*)pw + boff) = f2bf(pv[f][r]);
        }
      bf16x8_t pa[2];
#pragma unroll
      for (int s = 0; s < 2; s++) {
        int boff = (lr * 128 + s * 64 + lg * 16) ^ ((lr & 7) << 4);
        pa[s] = *(const bf16x8_t*)((const char*)pw + boff);
      }
#pragma unroll
      for (int fn = 0; fn < 4; fn++) {
        int row = fn * 16 + lr;
#pragma unroll
        for (int s = 0; s < 2; s++) {
          int boff = (row * 128 + s * 64 + lg * 16) ^ ((row & 7) << 4);
          bf16x8_t vf = *(const bf16x8_t*)((const char*)Vls + boff);
          oacc[fn] = __builtin_amdgcn_mfma_f32_16x16x32_bf16(pa[s], vf, oacc[fn], 0, 0, 0);
        }
      }
    }

    // deferred l reduction over the 16-lane row group
#pragma unroll
    for (int mask = 1; mask < 16; mask <<= 1)
#pragma unroll
      for (int r = 0; r < 4; r++)
        lsum[r] += __shfl_xor(lsum[r], mask, 64);
    float rinv[4];
#pragma unroll
    for (int r = 0; r < 4; r++) rinv[r] = 1.0f / lsum[r];

#pragma unroll
    for (int fn = 0; fn < 4; fn++)
#pragma unroll
      for (int r = 0; r < 4; r++) {
        int n_idx = qb + lg * 4 + r;
        float v = oacc[fn][r] * rinv[r];
        O[((size_t)(b * NN + n_idx)) * DD + h * HDD + fn * 16 + lr] = f2bf(v);
      }
  }
}

extern "C" void kernel_launch(void* const* d_in, const int* in_sizes, int n_in,
                              void* d_out, int out_size, void* d_ws, size_t ws_size,
                              hipStream_t stream) {
  const float* x  = (const float*)d_in[0];
  const float* Wq = (const float*)d_in[1];
  const float* Wk = (const float*)d_in[2];
  const float* Wv = (const float*)d_in[3];
  const float* Wo = (const float*)d_in[4];
  const float* Wf = (const float*)d_in[5];
  float* out = (float*)d_out;
  char* ws = (char*)d_ws;
  const size_t MB = 1024 * 1024;
  u16* x_bf = (u16*)(ws + 0);        // 8 MB
  u16* WqT  = (u16*)(ws + 8  * MB);  // 2 MB each
  u16* WkT  = (u16*)(ws + 10 * MB);
  u16* WvT  = (u16*)(ws + 12 * MB);
  u16* WoT  = (u16*)(ws + 14 * MB);
  u16* Qw   = (u16*)(ws + 16 * MB);  // 8 MB [bh][n][hd]
  u16* Kw   = (u16*)(ws + 24 * MB);  // 8 MB
  u16* Vw   = (u16*)(ws + 32 * MB);  // 8 MB [bh][hd][n]
  u16* Ow   = (u16*)(ws + 40 * MB);  // 8 MB [b n d]
  float* lf = (float*)(ws + 48 * MB);            // 256 KB
  float* cwp = (float*)(ws + 48 * MB + 262144);  // 256 KB
  u16* Vtmp = (u16*)(ws + 49 * MB);  // 8 MB [bh][n][hd]

  transpose_w_kernel<<<256, 256, 0, stream>>>(Wq, WqT);
  transpose_w_kernel<<<256, 256, 0, stream>>>(Wk, WkT);
  transpose_w_kernel<<<256, 256, 0, stream>>>(Wv, WvT);
  transpose_w_kernel<<<256, 256, 0, stream>>>(Wo, WoT);
  logf_kernel<<<4096, 256, 0, stream>>>(x, Wf, lf, x_bf);
  cumsum_kernel<<<32, 64, 0, stream>>>(lf, cwp);
  dim3 gg(8, 32);
  gemm_kernel<<<gg, 256, 0, stream>>>(x_bf, WqT, Qw, 0);
  gemm_kernel<<<gg, 256, 0, stream>>>(x_bf, WkT, Kw, 0);
  gemm_kernel<<<gg, 256, 0, stream>>>(x_bf, WvT, Vtmp, 0);
  transpose_v_kernel<<<dim3(32, 32), 256, 0, stream>>>(Vtmp, Vw);
  attn_kernel<<<dim3(16, 32), 256, 0, stream>>>(Qw, Kw, Vw, cwp, Ow);
  gemm_kernel<<<gg, 256, 0, stream>>>(Ow, WoT, out, 1);
}

// Round 4
// 177.601 us; speedup vs baseline: 1.6367x; 1.2324x over previous
//
#include <hip/hip_runtime.h>
#include <hip/hip_bf16.h>
#include <stdint.h>

#define NN 2048
#define DD 1024
#define HH 16
#define HDD 64
#define QBLK 64
#define KVBLK 64

typedef unsigned short u16;
typedef __attribute__((ext_vector_type(8))) __bf16 bf16x8_t;
typedef __attribute__((ext_vector_type(4))) float f32x4_t;

static __device__ __forceinline__ u16 f2bf(float f) {
  union { float f; uint32_t u; } v; v.f = f;
  uint32_t r = v.u + 0x7FFFu + ((v.u >> 16) & 1u);
  return (u16)(r >> 16);
}

// async global->LDS, 16B per lane. LDS dest must be wave-uniform base + lane*16.
static __device__ __forceinline__ void async_copy16(const void* g, void* l) {
  __builtin_amdgcn_global_load_lds((const __attribute__((address_space(1))) void*)g,
                                   (__attribute__((address_space(3))) void*)l, 16, 0, 0);
}

// ---------------- weight transpose+cast: Wt[n][k] = W[k][n], 4 weights in one launch ----------------
__global__ void transpose_w_kernel(const float* __restrict__ W0, const float* __restrict__ W1,
                                   const float* __restrict__ W2, const float* __restrict__ W3,
                                   u16* __restrict__ Wt) {
  __shared__ float tile[64][65];
  const float* W = blockIdx.y == 0 ? W0 : blockIdx.y == 1 ? W1 : blockIdx.y == 2 ? W2 : W3;
  u16* out = Wt + (size_t)blockIdx.y * DD * DD;
  int bx = blockIdx.x & 15;   // n tile
  int by = blockIdx.x >> 4;   // k tile
  int t = threadIdx.x;
  int c = t & 63, r4 = t >> 6;
#pragma unroll
  for (int i = 0; i < 16; i++) {
    int row = i * 4 + r4;
    tile[row][c] = W[(by * 64 + row) * DD + bx * 64 + c];
  }
  __syncthreads();
#pragma unroll
  for (int i = 0; i < 16; i++) {
    int row = i * 4 + r4;
    out[(bx * 64 + row) * DD + by * 64 + c] = f2bf(tile[c][row]);
  }
}

// ---------------- log-sigmoid gate + fused x->bf16 cast ----------------
__global__ void logf_kernel(const float* __restrict__ x, const float* __restrict__ Wf,
                            float* __restrict__ lf, u16* __restrict__ xb) {
  __shared__ float xs[DD];
  __shared__ float part[16][17];
  int row = blockIdx.x;   // b*N + n
  int t = threadIdx.x;    // 256
  float4 v = *(const float4*)&x[(size_t)row * DD + t * 4];
  *(float4*)&xs[t * 4] = v;
  ushort4 o;
  o.x = f2bf(v.x); o.y = f2bf(v.y); o.z = f2bf(v.z); o.w = f2bf(v.w);
  *(ushort4*)&xb[(size_t)row * DD + t * 4] = o;
  __syncthreads();
  int h = t & 15, chunk = t >> 4;
  float s = 0.f;
#pragma unroll 8
  for (int e = 0; e < 64; e++)
    s += xs[chunk * 64 + e] * Wf[(chunk * 64 + e) * HH + h];
  part[chunk][h] = s;
  __syncthreads();
  if (t < 16) {
    float z = 0.f;
#pragma unroll
    for (int i = 0; i < 16; i++) z += part[i][t];
    float ls = fminf(z, 0.f) - log1pf(__expf(-fabsf(z)));
    int b = row >> 11, n = row & (NN - 1);
    lf[(b * HH + t) * NN + n] = ls;
  }
}

// ---------------- cumsum over n per (b,h): float4/lane, 8 outer iters ----------------
__global__ void cumsum_kernel(const float* __restrict__ lf, float* __restrict__ c) {
  int bh = blockIdx.x;
  int lane = threadIdx.x;  // 64
  const float* in = lf + bh * NN;
  float* out = c + bh * NN;
  float carry = 0.f;
  for (int t0 = 0; t0 < NN; t0 += 256) {
    float4 v = *(const float4*)&in[t0 + lane * 4];
    float s1 = v.x + v.y, s2 = s1 + v.z, s3 = s2 + v.w;
    float incl = s3;
#pragma unroll
    for (int off = 1; off < 64; off <<= 1) {
      float u = __shfl_up(incl, off, 64);
      if (lane >= off) incl += u;
    }
    float excl = incl - s3 + carry;
    float4 o;
    o.x = excl + v.x; o.y = excl + s1; o.z = excl + s2; o.w = excl + s3;
    *(float4*)&out[t0 + lane * 4] = o;
    carry = __shfl(incl, 63, 64) + carry;
  }
}

// ---------------- GEMM 128x128 tile, BK=64, swizzled LDS ----------------
// mode 0 (QKV fused): Wt is [3072][1024]; n-range selects oQ/oK/oV, bf16 [bh][n][hd]
// mode 1 (output):    Wt is [1024][1024]; fp32 flat to oF
__global__ __launch_bounds__(256) void gemm_kernel(const u16* __restrict__ A,
                                                   const u16* __restrict__ Wt,
                                                   u16* __restrict__ oQ, u16* __restrict__ oK,
                                                   u16* __restrict__ oV, float* __restrict__ oF,
                                                   int mode) {
  __shared__ u16 Als[128 * 64];
  __shared__ u16 Bls[128 * 64];
  int m0 = blockIdx.y * 128, n0 = blockIdx.x * 128;
  int tid = threadIdx.x;
  int lane = tid & 63, w = tid >> 6;
  int wm = w >> 1, wn = w & 1;
  int lr = lane & 15, lg = lane >> 4;

  // staging: slots s = tid + j*256 (j=0..3). row = s>>3, chunk = s&7 (16B units).
  // LDS linear at s*16; swizzle folded into SOURCE chunk: chunk ^ (row&7).
  const u16* gA[4]; const u16* gB[4]; u16* lA[4]; u16* lB[4];
#pragma unroll
  for (int j = 0; j < 4; j++) {
    int s = tid + j * 256;
    int row = s >> 3, ch = s & 7;
    int scol = (ch ^ (row & 7)) * 8;
    gA[j] = &A [(size_t)(m0 + row) * DD + scol];
    gB[j] = &Wt[(size_t)(n0 + row) * DD + scol];
    lA[j] = &Als[s * 8];
    lB[j] = &Bls[s * 8];
  }

  f32x4_t acc[4][4];
#pragma unroll
  for (int i = 0; i < 4; i++)
#pragma unroll
    for (int j = 0; j < 4; j++) acc[i][j] = (f32x4_t){0.f, 0.f, 0.f, 0.f};

  for (int kt = 0; kt < DD; kt += 64) {
    __syncthreads();
#pragma unroll
    for (int j = 0; j < 4; j++) {
      async_copy16(gA[j] + kt, lA[j]);
      async_copy16(gB[j] + kt, lB[j]);
    }
    __syncthreads();
#pragma unroll
    for (int kk = 0; kk < 2; kk++) {
      bf16x8_t af[4], bfv[4];
#pragma unroll
      for (int mi = 0; mi < 4; mi++) {
        int row = wm * 64 + mi * 16 + lr;
        int boff = (row * 128 + kk * 64 + lg * 16) ^ ((row & 7) << 4);
        af[mi] = *(const bf16x8_t*)((const char*)Als + boff);
      }
#pragma unroll
      for (int ni = 0; ni < 4; ni++) {
        int row = wn * 64 + ni * 16 + lr;
        int boff = (row * 128 + kk * 64 + lg * 16) ^ ((row & 7) << 4);
        bfv[ni] = *(const bf16x8_t*)((const char*)Bls + boff);
      }
#pragma unroll
      for (int mi = 0; mi < 4; mi++)
#pragma unroll
        for (int ni = 0; ni < 4; ni++)
          acc[mi][ni] = __builtin_amdgcn_mfma_f32_16x16x32_bf16(af[mi], bfv[ni], acc[mi][ni], 0, 0, 0);
    }
  }

  if (mode == 1) {
#pragma unroll
    for (int mi = 0; mi < 4; mi++)
#pragma unroll
      for (int ni = 0; ni < 4; ni++) {
        int gcol = n0 + wn * 64 + ni * 16 + lr;
#pragma unroll
        for (int r = 0; r < 4; r++) {
          int grow = m0 + wm * 64 + mi * 16 + lg * 4 + r;
          oF[(size_t)grow * DD + gcol] = acc[mi][ni][r];
        }
      }
  } else {
    int which = n0 >> 10;
    u16* outp = which == 0 ? oQ : which == 1 ? oK : oV;
    int nl0 = n0 & 1023;
#pragma unroll
    for (int mi = 0; mi < 4; mi++)
#pragma unroll
      for (int ni = 0; ni < 4; ni++) {
        int gcol = nl0 + wn * 64 + ni * 16 + lr;
        int h = gcol >> 6, hd = gcol & 63;
#pragma unroll
        for (int r = 0; r < 4; r++) {
          int grow = m0 + wm * 64 + mi * 16 + lg * 4 + r;
          int b = grow >> 11, n = grow & (NN - 1);
          outp[((size_t)(b * HH + h) * NN + n) * HDD + hd] = f2bf(acc[mi][ni][r]);
        }
      }
  }
}

// ---------------- V transpose: [bh][n][hd] -> [bh][hd][n] ----------------
__global__ void transpose_v_kernel(const u16* __restrict__ Vtmp, u16* __restrict__ Vt) {
  __shared__ u16 tile[64][80];
  int bh = blockIdx.y;
  int n0 = blockIdx.x * 64;
  int t = threadIdx.x;
  const u16* src = Vtmp + (size_t)bh * NN * HDD;
  u16* dst = Vt + (size_t)bh * HDD * NN;
#pragma unroll
  for (int it = 0; it < 2; it++) {
    int cc = t + it * 256;
    int row = cc >> 3, p = cc & 7;
    *(uint4*)&tile[row][p * 8] = *(const uint4*)&src[(size_t)(n0 + row) * HDD + p * 8];
  }
  __syncthreads();
#pragma unroll
  for (int it = 0; it < 2; it++) {
    int cc = t + it * 256;
    int row = cc >> 3, p = cc & 7;
    union { u16 v[8]; uint4 q; } tmp;
#pragma unroll
    for (int e = 0; e < 8; e++) tmp.v[e] = tile[p * 8 + e][row];
    *(uint4*)&dst[(size_t)row * NN + n0 + p * 8] = tmp.q;
  }
}

// ---------------- flash attention with decay bias ----------------
// Fixed-max softmax, deferred l-reduction, 1024 independent blocks heavy-first.
__global__ __launch_bounds__(256) void attn_kernel(const u16* __restrict__ Q,
                                                   const u16* __restrict__ K,
                                                   const u16* __restrict__ Vt,
                                                   const float* __restrict__ cw,
                                                   u16* __restrict__ O) {
  __shared__ u16 Kls[KVBLK * 64];
  __shared__ u16 Vls[64 * KVBLK];
  __shared__ u16 Pls[4][16 * 64];
  int tile = 31 - blockIdx.x;  // heavy tiles dispatched first
  int bh = blockIdx.y;
  int tid = threadIdx.x;
  int lane = tid & 63, w = tid >> 6;
  int lr = lane & 15, lg = lane >> 4;
  const u16* Qh = Q + (size_t)bh * NN * HDD;
  const u16* Kh = K + (size_t)bh * NN * HDD;
  const u16* Vh = Vt + (size_t)bh * HDD * NN;
  const float* ch = cw + bh * NN;
  int b = bh >> 4, h = bh & 15;

  // staging: 512 slots of 16B per 8KB tile; slot -> (row=slot>>3, chunk=slot&7),
  // LDS linear at slot*16B; swizzle folded into SOURCE chunk: chunk ^ (row&7).
  int s0 = tid, s1 = tid + 256;
  int r0 = s0 >> 3, p0 = s0 & 7;
  int r1 = s1 >> 3, p1 = s1 & 7;
  const u16* gk0 = &Kh[(size_t)r0 * HDD + ((p0 ^ (r0 & 7)) * 8)];
  const u16* gk1 = &Kh[(size_t)r1 * HDD + ((p1 ^ (r1 & 7)) * 8)];
  const u16* gv0 = &Vh[(size_t)r0 * NN + ((p0 ^ (r0 & 7)) * 8)];
  const u16* gv1 = &Vh[(size_t)r1 * NN + ((p1 ^ (r1 & 7)) * 8)];
  u16* lk0 = &Kls[s0 * 8];
  u16* lk1 = &Kls[s1 * 8];
  u16* lv0 = &Vls[s0 * 8];
  u16* lv1 = &Vls[s1 * 8];

  int qb = tile * QBLK + w * 16;

  bf16x8_t qf[2];
#pragma unroll
  for (int s = 0; s < 2; s++)
    qf[s] = *(const bf16x8_t*)&Qh[(size_t)(qb + lr) * HDD + s * 32 + lg * 8];
  float cq[4];
#pragma unroll
  for (int r = 0; r < 4; r++) cq[r] = ch[qb + lg * 4 + r];

  float lsum[4] = {0.f, 0.f, 0.f, 0.f};
  f32x4_t oacc[4];
#pragma unroll
  for (int fn = 0; fn < 4; fn++) oacc[fn] = (f32x4_t){0.f, 0.f, 0.f, 0.f};

  for (int kvt = 0; kvt <= tile; kvt++) {
    int kv0 = kvt * KVBLK;
    __syncthreads();
    async_copy16(gk0 + (size_t)kv0 * HDD, lk0);
    async_copy16(gk1 + (size_t)kv0 * HDD, lk1);
    async_copy16(gv0 + kv0, lv0);
    async_copy16(gv1 + kv0, lv1);
    __syncthreads();
    float ck[4];
#pragma unroll
    for (int f = 0; f < 4; f++) ck[f] = ch[kv0 + f * 16 + lr];

    // QK^T
    f32x4_t sacc[4];
#pragma unroll
    for (int f = 0; f < 4; f++) sacc[f] = (f32x4_t){0.f, 0.f, 0.f, 0.f};
#pragma unroll
    for (int f = 0; f < 4; f++) {
      int row = f * 16 + lr;
#pragma unroll
      for (int s = 0; s < 2; s++) {
        int boff = (row * 128 + s * 64 + lg * 16) ^ ((row & 7) << 4);
        bf16x8_t kf = *(const bf16x8_t*)((const char*)Kls + boff);
        sacc[f] = __builtin_amdgcn_mfma_f32_16x16x32_bf16(qf[s], kf, sacc[f], 0, 0, 0);
      }
    }

    // fixed-max softmax: p = exp(score); per-lane partial l
    bool diag = (kvt == tile);
    float pv[4][4];
#pragma unroll
    for (int f = 0; f < 4; f++) {
      int j = kv0 + f * 16 + lr;
#pragma unroll
      for (int r = 0; r < 4; r++) {
        float val = fmaf(sacc[f][r], 0.125f, cq[r] - ck[f]);
        float e = __expf(val);
        if (diag && j > qb + lg * 4 + r) e = 0.f;
        pv[f][r] = e; lsum[r] += e;
      }
    }

    // P -> LDS (D-layout write, A-layout read), per-wave buffer, swizzled.
    // packed cvt (v_cvt_pk_bf16_f32 via __float22bfloat162_rn)
    u16* pw = (u16*)Pls[w];
#pragma unroll
    for (int f = 0; f < 4; f++)
#pragma unroll
      for (int r = 0; r < 4; r += 2) {
        __hip_bfloat162 h2 = __float22bfloat162_rn(make_float2(pv[f][r], pv[f][r + 1]));
        union { __hip_bfloat162 h; uint32_t u; } cvt; cvt.h = h2;
        int col = f * 16 + lr;
        int row0 = lg * 4 + r;
        int b0 = (row0 * 128 + col * 2) ^ ((row0 & 7) << 4);
        int row1 = row0 + 1;
        int b1 = (row1 * 128 + col * 2) ^ ((row1 & 7) << 4);
        *(u16*)((char*)pw + b0) = (u16)cvt.u;
        *(u16*)((char*)pw + b1) = (u16)(cvt.u >> 16);
      }
    bf16x8_t pa[2];
#pragma unroll
    for (int s = 0; s < 2; s++) {
      int boff = (lr * 128 + s * 64 + lg * 16) ^ ((lr & 7) << 4);
      pa[s] = *(const bf16x8_t*)((const char*)pw + boff);
    }
#pragma unroll
    for (int fn = 0; fn < 4; fn++) {
      int row = fn * 16 + lr;
#pragma unroll
      for (int s = 0; s < 2; s++) {
        int boff = (row * 128 + s * 64 + lg * 16) ^ ((row & 7) << 4);
        bf16x8_t vf = *(const bf16x8_t*)((const char*)Vls + boff);
        oacc[fn] = __builtin_amdgcn_mfma_f32_16x16x32_bf16(pa[s], vf, oacc[fn], 0, 0, 0);
      }
    }
  }

  // deferred l reduction over the 16-lane row group
#pragma unroll
  for (int mask = 1; mask < 16; mask <<= 1)
#pragma unroll
    for (int r = 0; r < 4; r++)
      lsum[r] += __shfl_xor(lsum[r], mask, 64);
  float rinv[4];
#pragma unroll
  for (int r = 0; r < 4; r++) rinv[r] = 1.0f / lsum[r];

#pragma unroll
  for (int fn = 0; fn < 4; fn++)
#pragma unroll
    for (int r = 0; r < 4; r++) {
      int n_idx = qb + lg * 4 + r;
      float v = oacc[fn][r] * rinv[r];
      O[((size_t)(b * NN + n_idx)) * DD + h * HDD + fn * 16 + lr] = f2bf(v);
    }
}

extern "C" void kernel_launch(void* const* d_in, const int* in_sizes, int n_in,
                              void* d_out, int out_size, void* d_ws, size_t ws_size,
                              hipStream_t stream) {
  const float* x  = (const float*)d_in[0];
  const float* Wq = (const float*)d_in[1];
  const float* Wk = (const float*)d_in[2];
  const float* Wv = (const float*)d_in[3];
  const float* Wo = (const float*)d_in[4];
  const float* Wf = (const float*)d_in[5];
  float* out = (float*)d_out;
  char* ws = (char*)d_ws;
  const size_t MB = 1024 * 1024;
  u16* x_bf  = (u16*)(ws + 0);        // 8 MB
  u16* WqkvT = (u16*)(ws + 8 * MB);   // 6 MB: WqT | WkT | WvT contiguous [3072][1024]
  u16* WoT   = (u16*)(ws + 14 * MB);  // 2 MB
  u16* Qw    = (u16*)(ws + 16 * MB);  // 8 MB [bh][n][hd]
  u16* Kw    = (u16*)(ws + 24 * MB);  // 8 MB
  u16* Vw    = (u16*)(ws + 32 * MB);  // 8 MB [bh][hd][n]
  u16* Ow    = (u16*)(ws + 40 * MB);  // 8 MB [b n d]
  float* lf  = (float*)(ws + 48 * MB);            // 256 KB
  float* cwp = (float*)(ws + 48 * MB + 262144);   // 256 KB
  u16* Vtmp  = (u16*)(ws + 49 * MB);  // 8 MB [bh][n][hd]

  // Wt layout trick: transpose Wq,Wk,Wv into one contiguous [3072][1024] and Wo after it.
  transpose_w_kernel<<<dim3(256, 4), 256, 0, stream>>>(Wq, Wk, Wv, Wo, WqkvT);
  logf_kernel<<<4096, 256, 0, stream>>>(x, Wf, lf, x_bf);
  cumsum_kernel<<<32, 64, 0, stream>>>(lf, cwp);
  // fused QKV GEMM: N = 3072
  gemm_kernel<<<dim3(24, 32), 256, 0, stream>>>(x_bf, WqkvT, Qw, Kw, Vtmp, nullptr, 0);
  transpose_v_kernel<<<dim3(32, 32), 256, 0, stream>>>(Vtmp, Vw);
  attn_kernel<<<dim3(32, 32), 256, 0, stream>>>(Qw, Kw, Vw, cwp, Ow);
  gemm_kernel<<<dim3(8, 32), 256, 0, stream>>>(Ow, WqkvT + (size_t)3 * DD * DD, nullptr, nullptr, nullptr, out, 1);
}

// Round 5
// 141.192 us; speedup vs baseline: 2.0587x; 1.2579x over previous
//
#include <hip/hip_runtime.h>
#include <hip/hip_bf16.h>
#include <stdint.h>

#define NN 2048
#define DD 1024
#define HH 16
#define HDD 64
#define QBLK 64
#define KVBLK 64

typedef unsigned short u16;
typedef __attribute__((ext_vector_type(8))) __bf16 bf16x8_t;
typedef __attribute__((ext_vector_type(4))) float f32x4_t;

static __device__ __forceinline__ u16 f2bf(float f) {
  union { float f; uint32_t u; } v; v.f = f;
  uint32_t r = v.u + 0x7FFFu + ((v.u >> 16) & 1u);
  return (u16)(r >> 16);
}

// async global->LDS, 16B per lane. LDS dest must be wave-uniform base + lane*16.
static __device__ __forceinline__ void async_copy16(const void* g, void* l) {
  __builtin_amdgcn_global_load_lds((const __attribute__((address_space(1))) void*)g,
                                   (__attribute__((address_space(3))) void*)l, 16, 0, 0);
}

// ---------------- weight transpose+cast: Wt[n][k] = W[k][n], 4 weights in one launch ----------------
__global__ void transpose_w_kernel(const float* __restrict__ W0, const float* __restrict__ W1,
                                   const float* __restrict__ W2, const float* __restrict__ W3,
                                   u16* __restrict__ Wt) {
  __shared__ float tile[64][65];
  const float* W = blockIdx.y == 0 ? W0 : blockIdx.y == 1 ? W1 : blockIdx.y == 2 ? W2 : W3;
  u16* out = Wt + (size_t)blockIdx.y * DD * DD;
  int bx = blockIdx.x & 15;   // n tile
  int by = blockIdx.x >> 4;   // k tile
  int t = threadIdx.x;
  int c = t & 63, r4 = t >> 6;
#pragma unroll
  for (int i = 0; i < 16; i++) {
    int row = i * 4 + r4;
    tile[row][c] = W[(by * 64 + row) * DD + bx * 64 + c];
  }
  __syncthreads();
#pragma unroll
  for (int i = 0; i < 16; i++) {
    int row = i * 4 + r4;
    out[(bx * 64 + row) * DD + by * 64 + c] = f2bf(tile[c][row]);
  }
}

// ---------------- log-sigmoid gate + fused x->bf16 cast ----------------
__global__ void logf_kernel(const float* __restrict__ x, const float* __restrict__ Wf,
                            float* __restrict__ lf, u16* __restrict__ xb) {
  __shared__ float xs[DD];
  __shared__ float part[16][17];
  int row = blockIdx.x;   // b*N + n
  int t = threadIdx.x;    // 256
  float4 v = *(const float4*)&x[(size_t)row * DD + t * 4];
  *(float4*)&xs[t * 4] = v;
  ushort4 o;
  o.x = f2bf(v.x); o.y = f2bf(v.y); o.z = f2bf(v.z); o.w = f2bf(v.w);
  *(ushort4*)&xb[(size_t)row * DD + t * 4] = o;
  __syncthreads();
  int h = t & 15, chunk = t >> 4;
  float s = 0.f;
#pragma unroll 8
  for (int e = 0; e < 64; e++)
    s += xs[chunk * 64 + e] * Wf[(chunk * 64 + e) * HH + h];
  part[chunk][h] = s;
  __syncthreads();
  if (t < 16) {
    float z = 0.f;
#pragma unroll
    for (int i = 0; i < 16; i++) z += part[i][t];
    float ls = fminf(z, 0.f) - log1pf(__expf(-fabsf(z)));
    int b = row >> 11, n = row & (NN - 1);
    lf[(b * HH + t) * NN + n] = ls;
  }
}

// ---------------- cumsum over n per (b,h): float4/lane, 8 outer iters ----------------
__global__ void cumsum_kernel(const float* __restrict__ lf, float* __restrict__ c) {
  int bh = blockIdx.x;
  int lane = threadIdx.x;  // 64
  const float* in = lf + bh * NN;
  float* out = c + bh * NN;
  float carry = 0.f;
  for (int t0 = 0; t0 < NN; t0 += 256) {
    float4 v = *(const float4*)&in[t0 + lane * 4];
    float s1 = v.x + v.y, s2 = s1 + v.z, s3 = s2 + v.w;
    float incl = s3;
#pragma unroll
    for (int off = 1; off < 64; off <<= 1) {
      float u = __shfl_up(incl, off, 64);
      if (lane >= off) incl += u;
    }
    float excl = incl - s3 + carry;
    float4 o;
    o.x = excl + v.x; o.y = excl + s1; o.z = excl + s2; o.w = excl + s3;
    *(float4*)&out[t0 + lane * 4] = o;
    carry = __shfl(incl, 63, 64) + carry;
  }
}

// ---------------- GEMM 128x128 tile, BK=64, swizzled LDS ----------------
// mode 0 (QKV fused): Wt is [3072][1024]; n-range selects oQ/oK/oV, bf16 [bh][n][hd]
// mode 1 (output):    Wt is [1024][1024]; fp32 flat to oF
__global__ __launch_bounds__(256) void gemm_kernel(const u16* __restrict__ A,
                                                   const u16* __restrict__ Wt,
                                                   u16* __restrict__ oQ, u16* __restrict__ oK,
                                                   u16* __restrict__ oV, float* __restrict__ oF,
                                                   int mode) {
  __shared__ u16 Als[128 * 64];
  __shared__ u16 Bls[128 * 64];
  int m0 = blockIdx.y * 128, n0 = blockIdx.x * 128;
  int tid = threadIdx.x;
  int lane = tid & 63, w = tid >> 6;
  int wm = w >> 1, wn = w & 1;
  int lr = lane & 15, lg = lane >> 4;

  // staging: slots s = tid + j*256 (j=0..3). row = s>>3, chunk = s&7 (16B units).
  // LDS linear at s*16; swizzle folded into SOURCE chunk: chunk ^ (row&7).
  const u16* gA[4]; const u16* gB[4]; u16* lA[4]; u16* lB[4];
#pragma unroll
  for (int j = 0; j < 4; j++) {
    int s = tid + j * 256;
    int row = s >> 3, ch = s & 7;
    int scol = (ch ^ (row & 7)) * 8;
    gA[j] = &A [(size_t)(m0 + row) * DD + scol];
    gB[j] = &Wt[(size_t)(n0 + row) * DD + scol];
    lA[j] = &Als[s * 8];
    lB[j] = &Bls[s * 8];
  }

  f32x4_t acc[4][4];
#pragma unroll
  for (int i = 0; i < 4; i++)
#pragma unroll
    for (int j = 0; j < 4; j++) acc[i][j] = (f32x4_t){0.f, 0.f, 0.f, 0.f};

  for (int kt = 0; kt < DD; kt += 64) {
    __syncthreads();
#pragma unroll
    for (int j = 0; j < 4; j++) {
      async_copy16(gA[j] + kt, lA[j]);
      async_copy16(gB[j] + kt, lB[j]);
    }
    __syncthreads();
#pragma unroll
    for (int kk = 0; kk < 2; kk++) {
      bf16x8_t af[4], bfv[4];
#pragma unroll
      for (int mi = 0; mi < 4; mi++) {
        int row = wm * 64 + mi * 16 + lr;
        int boff = (row * 128 + kk * 64 + lg * 16) ^ ((row & 7) << 4);
        af[mi] = *(const bf16x8_t*)((const char*)Als + boff);
      }
#pragma unroll
      for (int ni = 0; ni < 4; ni++) {
        int row = wn * 64 + ni * 16 + lr;
        int boff = (row * 128 + kk * 64 + lg * 16) ^ ((row & 7) << 4);
        bfv[ni] = *(const bf16x8_t*)((const char*)Bls + boff);
      }
#pragma unroll
      for (int mi = 0; mi < 4; mi++)
#pragma unroll
        for (int ni = 0; ni < 4; ni++)
          acc[mi][ni] = __builtin_amdgcn_mfma_f32_16x16x32_bf16(af[mi], bfv[ni], acc[mi][ni], 0, 0, 0);
    }
  }

  if (mode == 1) {
#pragma unroll
    for (int mi = 0; mi < 4; mi++)
#pragma unroll
      for (int ni = 0; ni < 4; ni++) {
        int gcol = n0 + wn * 64 + ni * 16 + lr;
#pragma unroll
        for (int r = 0; r < 4; r++) {
          int grow = m0 + wm * 64 + mi * 16 + lg * 4 + r;
          oF[(size_t)grow * DD + gcol] = acc[mi][ni][r];
        }
      }
  } else {
    int which = n0 >> 10;
    u16* outp = which == 0 ? oQ : which == 1 ? oK : oV;
    int nl0 = n0 & 1023;
#pragma unroll
    for (int mi = 0; mi < 4; mi++)
#pragma unroll
      for (int ni = 0; ni < 4; ni++) {
        int gcol = nl0 + wn * 64 + ni * 16 + lr;
        int h = gcol >> 6, hd = gcol & 63;
#pragma unroll
        for (int r = 0; r < 4; r++) {
          int grow = m0 + wm * 64 + mi * 16 + lg * 4 + r;
          int b = grow >> 11, n = grow & (NN - 1);
          outp[((size_t)(b * HH + h) * NN + n) * HDD + hd] = f2bf(acc[mi][ni][r]);
        }
      }
  }
}

// ---------------- V transpose: [bh][n][hd] -> [bh][hd][n] ----------------
__global__ void transpose_v_kernel(const u16* __restrict__ Vtmp, u16* __restrict__ Vt) {
  __shared__ u16 tile[64][80];
  int bh = blockIdx.y;
  int n0 = blockIdx.x * 64;
  int t = threadIdx.x;
  const u16* src = Vtmp + (size_t)bh * NN * HDD;
  u16* dst = Vt + (size_t)bh * HDD * NN;
#pragma unroll
  for (int it = 0; it < 2; it++) {
    int cc = t + it * 256;
    int row = cc >> 3, p = cc & 7;
    *(uint4*)&tile[row][p * 8] = *(const uint4*)&src[(size_t)(n0 + row) * HDD + p * 8];
  }
  __syncthreads();
#pragma unroll
  for (int it = 0; it < 2; it++) {
    int cc = t + it * 256;
    int row = cc >> 3, p = cc & 7;
    union { u16 v[8]; uint4 q; } tmp;
#pragma unroll
    for (int e = 0; e < 8; e++) tmp.v[e] = tile[p * 8 + e][row];
    *(uint4*)&dst[(size_t)row * NN + n0 + p * 8] = tmp.q;
  }
}

// ---------------- flash attention with decay bias ----------------
// Fixed-max softmax, deferred l-reduction, paired q-tiles (t,31-t) = uniform 33 iters,
// double-buffered K/V staging: issue next tile's global_load_lds BEFORE compute,
// single barrier per iter -> load latency hides under QK/softmax/PV.
__global__ __launch_bounds__(256) void attn_kernel(const u16* __restrict__ Q,
                                                   const u16* __restrict__ K,
                                                   const u16* __restrict__ Vt,
                                                   const float* __restrict__ cw,
                                                   u16* __restrict__ O) {
  __shared__ u16 Kls[2][KVBLK * 64];
  __shared__ u16 Vls[2][64 * KVBLK];
  __shared__ u16 Pls[4][16 * 64];
  int pidx = blockIdx.x, bh = blockIdx.y;
  int tid = threadIdx.x;
  int lane = tid & 63, w = tid >> 6;
  int lr = lane & 15, lg = lane >> 4;
  const u16* Qh = Q + (size_t)bh * NN * HDD;
  const u16* Kh = K + (size_t)bh * NN * HDD;
  const u16* Vh = Vt + (size_t)bh * HDD * NN;
  const float* ch = cw + bh * NN;
  int b = bh >> 4, h = bh & 15;

  // staging: 512 slots of 16B per 8KB tile; slot -> (row=slot>>3, chunk=slot&7),
  // LDS linear at slot*16B; swizzle folded into SOURCE chunk: chunk ^ (row&7).
  int s0 = tid, s1 = tid + 256;
  int r0 = s0 >> 3, p0 = s0 & 7;
  int r1 = s1 >> 3, p1 = s1 & 7;
  const u16* gk0 = &Kh[(size_t)r0 * HDD + ((p0 ^ (r0 & 7)) * 8)];
  const u16* gk1 = &Kh[(size_t)r1 * HDD + ((p1 ^ (r1 & 7)) * 8)];
  const u16* gv0 = &Vh[(size_t)r0 * NN + ((p0 ^ (r0 & 7)) * 8)];
  const u16* gv1 = &Vh[(size_t)r1 * NN + ((p1 ^ (r1 & 7)) * 8)];

  for (int which = 0; which < 2; which++) {
    int tile = which == 0 ? (31 - pidx) : pidx;
    int qb = tile * QBLK + w * 16;

    bf16x8_t qf[2];
#pragma unroll
    for (int s = 0; s < 2; s++)
      qf[s] = *(const bf16x8_t*)&Qh[(size_t)(qb + lr) * HDD + s * 32 + lg * 8];
    float cq[4];
#pragma unroll
    for (int r = 0; r < 4; r++) cq[r] = ch[qb + lg * 4 + r];

    float lsum[4] = {0.f, 0.f, 0.f, 0.f};
    f32x4_t oacc[4];
#pragma unroll
    for (int fn = 0; fn < 4; fn++) oacc[fn] = (f32x4_t){0.f, 0.f, 0.f, 0.f};

    // prologue: stage kv tile 0 into buffer 0
    async_copy16(gk0, &Kls[0][s0 * 8]);
    async_copy16(gk1, &Kls[0][s1 * 8]);
    async_copy16(gv0, &Vls[0][s0 * 8]);
    async_copy16(gv1, &Vls[0][s1 * 8]);
    __syncthreads();

    int cur = 0;
    for (int kvt = 0; kvt <= tile; kvt++) {
      // stage next tile into the other buffer BEFORE computing this one
      if (kvt < tile) {
        int nb = cur ^ 1;
        size_t kvn = (size_t)(kvt + 1) * KVBLK;
        async_copy16(gk0 + kvn * HDD, &Kls[nb][s0 * 8]);
        async_copy16(gk1 + kvn * HDD, &Kls[nb][s1 * 8]);
        async_copy16(gv0 + kvn, &Vls[nb][s0 * 8]);
        async_copy16(gv1 + kvn, &Vls[nb][s1 * 8]);
      }
      int kv0 = kvt * KVBLK;
      const u16* Kb = Kls[cur];
      const u16* Vb = Vls[cur];
      float ck[4];
#pragma unroll
      for (int f = 0; f < 4; f++) ck[f] = ch[kv0 + f * 16 + lr];

      // QK^T
      f32x4_t sacc[4];
#pragma unroll
      for (int f = 0; f < 4; f++) sacc[f] = (f32x4_t){0.f, 0.f, 0.f, 0.f};
#pragma unroll
      for (int f = 0; f < 4; f++) {
        int row = f * 16 + lr;
#pragma unroll
        for (int s = 0; s < 2; s++) {
          int boff = (row * 128 + s * 64 + lg * 16) ^ ((row & 7) << 4);
          bf16x8_t kf = *(const bf16x8_t*)((const char*)Kb + boff);
          sacc[f] = __builtin_amdgcn_mfma_f32_16x16x32_bf16(qf[s], kf, sacc[f], 0, 0, 0);
        }
      }

      // fixed-max softmax: p = exp(score); per-lane partial l
      bool diag = (kvt == tile);
      float pv[4][4];
#pragma unroll
      for (int f = 0; f < 4; f++) {
        int j = kv0 + f * 16 + lr;
#pragma unroll
        for (int r = 0; r < 4; r++) {
          float val = fmaf(sacc[f][r], 0.125f, cq[r] - ck[f]);
          float e = __expf(val);
          if (diag && j > qb + lg * 4 + r) e = 0.f;
          pv[f][r] = e; lsum[r] += e;
        }
      }

      // P -> LDS (D-layout write, A-layout read), per-wave buffer, swizzled.
      // packed cvt (v_cvt_pk_bf16_f32 via __float22bfloat162_rn)
      u16* pw = (u16*)Pls[w];
#pragma unroll
      for (int f = 0; f < 4; f++)
#pragma unroll
        for (int r = 0; r < 4; r += 2) {
          __hip_bfloat162 h2 = __float22bfloat162_rn(make_float2(pv[f][r], pv[f][r + 1]));
          union { __hip_bfloat162 hh; uint32_t u; } cvt; cvt.hh = h2;
          int col = f * 16 + lr;
          int row0 = lg * 4 + r;
          int b0 = (row0 * 128 + col * 2) ^ ((row0 & 7) << 4);
          int row1 = row0 + 1;
          int b1 = (row1 * 128 + col * 2) ^ ((row1 & 7) << 4);
          *(u16*)((char*)pw + b0) = (u16)cvt.u;
          *(u16*)((char*)pw + b1) = (u16)(cvt.u >> 16);
        }
      bf16x8_t pa[2];
#pragma unroll
      for (int s = 0; s < 2; s++) {
        int boff = (lr * 128 + s * 64 + lg * 16) ^ ((lr & 7) << 4);
        pa[s] = *(const bf16x8_t*)((const char*)pw + boff);
      }
#pragma unroll
      for (int fn = 0; fn < 4; fn++) {
        int row = fn * 16 + lr;
#pragma unroll
        for (int s = 0; s < 2; s++) {
          int boff = (row * 128 + s * 64 + lg * 16) ^ ((row & 7) << 4);
          bf16x8_t vf = *(const bf16x8_t*)((const char*)Vb + boff);
          oacc[fn] = __builtin_amdgcn_mfma_f32_16x16x32_bf16(pa[s], vf, oacc[fn], 0, 0, 0);
        }
      }
      __syncthreads();
      cur ^= 1;
    }

    // deferred l reduction over the 16-lane row group
#pragma unroll
    for (int mask = 1; mask < 16; mask <<= 1)
#pragma unroll
      for (int r = 0; r < 4; r++)
        lsum[r] += __shfl_xor(lsum[r], mask, 64);
    float rinv[4];
#pragma unroll
    for (int r = 0; r < 4; r++) rinv[r] = 1.0f / lsum[r];

#pragma unroll
    for (int fn = 0; fn < 4; fn++)
#pragma unroll
      for (int r = 0; r < 4; r++) {
        int n_idx = qb + lg * 4 + r;
        float v = oacc[fn][r] * rinv[r];
        O[((size_t)(b * NN + n_idx)) * DD + h * HDD + fn * 16 + lr] = f2bf(v);
      }
  }
}

extern "C" void kernel_launch(void* const* d_in, const int* in_sizes, int n_in,
                              void* d_out, int out_size, void* d_ws, size_t ws_size,
                              hipStream_t stream) {
  const float* x  = (const float*)d_in[0];
  const float* Wq = (const float*)d_in[1];
  const float* Wk = (const float*)d_in[2];
  const float* Wv = (const float*)d_in[3];
  const float* Wo = (const float*)d_in[4];
  const float* Wf = (const float*)d_in[5];
  float* out = (float*)d_out;
  char* ws = (char*)d_ws;
  const size_t MB = 1024 * 1024;
  u16* x_bf  = (u16*)(ws + 0);        // 8 MB
  u16* WqkvT = (u16*)(ws + 8 * MB);   // 6 MB: WqT | WkT | WvT contiguous [3072][1024]
  u16* WoT   = (u16*)(ws + 14 * MB);  // 2 MB
  u16* Qw    = (u16*)(ws + 16 * MB);  // 8 MB [bh][n][hd]
  u16* Kw    = (u16*)(ws + 24 * MB);  // 8 MB
  u16* Vw    = (u16*)(ws + 32 * MB);  // 8 MB [bh][hd][n]
  u16* Ow    = (u16*)(ws + 40 * MB);  // 8 MB [b n d]
  float* lf  = (float*)(ws + 48 * MB);            // 256 KB
  float* cwp = (float*)(ws + 48 * MB + 262144);   // 256 KB
  u16* Vtmp  = (u16*)(ws + 49 * MB);  // 8 MB [bh][n][hd]

  transpose_w_kernel<<<dim3(256, 4), 256, 0, stream>>>(Wq, Wk, Wv, Wo, WqkvT);
  logf_kernel<<<4096, 256, 0, stream>>>(x, Wf, lf, x_bf);
  cumsum_kernel<<<32, 64, 0, stream>>>(lf, cwp);
  // fused QKV GEMM: N = 3072
  gemm_kernel<<<dim3(24, 32), 256, 0, stream>>>(x_bf, WqkvT, Qw, Kw, Vtmp, nullptr, 0);
  transpose_v_kernel<<<dim3(32, 32), 256, 0, stream>>>(Vtmp, Vw);
  attn_kernel<<<dim3(16, 32), 256, 0, stream>>>(Qw, Kw, Vw, cwp, Ow);
  gemm_kernel<<<dim3(8, 32), 256, 0, stream>>>(Ow, WqkvT + (size_t)3 * DD * DD, nullptr, nullptr, nullptr, out, 1);
}